// Round 3
// baseline (3907.853 us; speedup 1.0000x reference)
//
#include <hip/hip_runtime.h>
#include <hip/hip_bf16.h>

typedef __hip_bfloat16 bf16;

#define NB 2
#define SEQ 2048
#define DIN 1024
#define NH 16
#define DH 64
#define DMODEL 1024  // NH*DH

__device__ __forceinline__ float bf2f(unsigned short u) {
    return __uint_as_float(((unsigned)u) << 16);
}
__device__ __forceinline__ unsigned short f2bf(float f) {
    unsigned u = __float_as_uint(f);
    unsigned r = (u + 0x7FFFu + ((u >> 16) & 1u)) >> 16;  // RNE
    return (unsigned short)r;
}
// read input element idx as float, per flag
__device__ __forceinline__ float ldin(const void* p, size_t idx, int isbf) {
    return isbf ? bf2f(((const unsigned short*)p)[idx]) : ((const float*)p)[idx];
}

// ---------------------------------------------------------------------------
// dtype detector: flags[0]=1 if float inputs are bf16, flags[1]=1 if mask is
// int32 (else 1-byte bool). Deterministic on pristine inputs; graph-safe.
// float32 read as bf16 pairs: even ushorts are mantissa fragments -> garbage
// exponents (~15% in sane range). bf16 N(0,1): ~100% sane.
// int32 mask: values all in {0,1}. byte mask read as int32: ~12% in {0,1}.
// ---------------------------------------------------------------------------
__global__ void detect(const unsigned short* q, const int* mask_i, int* flags) {
    __shared__ int cnt[2];
    int t = threadIdx.x;
    if (t < 2) cnt[t] = 0;
    __syncthreads();
    unsigned short u = q[2 * t];
    int e = (u >> 7) & 0xFF;
    int sane = (u == 0 || (e > 100 && e < 140)) ? 1 : 0;
    int v = mask_i[t];
    int zo = (v == 0 || v == 1) ? 1 : 0;
    atomicAdd(&cnt[0], sane);
    atomicAdd(&cnt[1], zo);
    __syncthreads();
    if (t == 0) {
        flags[0] = (cnt[0] >= 160) ? 1 : 0;
        flags[1] = (cnt[1] >= 230) ? 1 : 0;
    }
}

// ---------------------------------------------------------------------------
// Projection GEMM: C[n,h,k,d] = sum_m A[r=n*K+k][m] * W[h][m][d] + bias[h*64+d]
// A: (4096,1024), W: (16,1024,64), C: bf16 ws (n,h,k,d)
// Tile 64x64 (one head per col-tile), BK=32, 256 threads, 4x4 micro-tile.
// ---------------------------------------------------------------------------
__global__ __launch_bounds__(256) void proj_gemm(
    const void* __restrict__ Aq, const void* __restrict__ Ak, const void* __restrict__ Av,
    const void* __restrict__ Wq, const void* __restrict__ bq,
    const void* __restrict__ Wk, const void* __restrict__ bk,
    const void* __restrict__ Wv, const void* __restrict__ bv,
    unsigned short* __restrict__ qws, unsigned short* __restrict__ kws,
    unsigned short* __restrict__ vws, const int* __restrict__ flags)
{
    const int isbf = flags[0];
    const int z = blockIdx.z;
    const void* A    = (z == 0) ? Aq : (z == 1) ? Ak : Av;
    const void* W    = (z == 0) ? Wq : (z == 1) ? Wk : Wv;
    const void* bias = (z == 0) ? bq : (z == 1) ? bk : bv;
    unsigned short* C = (z == 0) ? qws : (z == 1) ? kws : vws;

    const int h  = blockIdx.x;
    const int c0 = h * 64;
    const int r0 = blockIdx.y * 64;
    const int tid = threadIdx.x;
    const int tx = tid & 15, ty = tid >> 4;

    __shared__ float As[32][68];  // As[m][r]
    __shared__ float Bs[32][68];  // Bs[m][c]

    float acc[4][4] = {};

    for (int m0 = 0; m0 < DIN; m0 += 32) {
        for (int i = tid; i < 64 * 32; i += 256) {
            int r = i >> 5, m = i & 31;
            As[m][r] = ldin(A, (size_t)(r0 + r) * DIN + m0 + m, isbf);
        }
        for (int i = tid; i < 32 * 64; i += 256) {
            int m = i >> 6, c = i & 63;
            Bs[m][c] = ldin(W, (size_t)h * DIN * DH + (size_t)(m0 + m) * DH + c, isbf);
        }
        __syncthreads();
#pragma unroll
        for (int mm = 0; mm < 32; ++mm) {
            float4 a4 = *(const float4*)&As[mm][ty * 4];
            float4 b4 = *(const float4*)&Bs[mm][tx * 4];
            float av[4] = {a4.x, a4.y, a4.z, a4.w};
            float bvv[4] = {b4.x, b4.y, b4.z, b4.w};
#pragma unroll
            for (int i = 0; i < 4; ++i)
#pragma unroll
                for (int j = 0; j < 4; ++j) acc[i][j] += av[i] * bvv[j];
        }
        __syncthreads();
    }

#pragma unroll
    for (int i = 0; i < 4; ++i) {
        int r = r0 + ty * 4 + i;
        int n = r >> 11, k = r & (SEQ - 1);
#pragma unroll
        for (int j = 0; j < 4; ++j) {
            int c = c0 + tx * 4 + j;
            int d = c & 63;
            float b = ldin(bias, c, isbf);
            C[(((size_t)n * NH + h) * SEQ + k) * DH + d] = f2bf(acc[i][j] + b);
        }
    }
}

// ---------------------------------------------------------------------------
// Attention: per block (n, h, 32-row Q tile); flash-style online softmax over
// 64-key tiles. q/k/v from bf16 ws (vectorized ushort4); mask dual-dtype.
// ---------------------------------------------------------------------------
__global__ __launch_bounds__(256) void attn(
    const unsigned short* __restrict__ qws, const unsigned short* __restrict__ kws,
    const unsigned short* __restrict__ vws, const void* __restrict__ mask,
    unsigned short* __restrict__ yws, const int* __restrict__ flags)
{
    const int mask_is_int = flags[1];
    const int qt = blockIdx.x;
    const int h  = blockIdx.y;
    const int n  = blockIdx.z;
    const int tid = threadIdx.x;
    const int r  = tid >> 3;
    const int q8 = tid & 7;

    __shared__ float ks[64][68];
    __shared__ float vs[64][68];
    __shared__ float qs[32][68];
    __shared__ float ps[32][68];

    const size_t base_nh = ((size_t)n * NH + h) * SEQ * DH;
    const int i0 = qt * 32;

    for (int i = tid; i < 32 * 16; i += 256) {
        int rr = i >> 4, seg = (i & 15) * 4;
        ushort4 t4 = *(const ushort4*)&qws[base_nh + (size_t)(i0 + rr) * DH + seg];
        qs[rr][seg + 0] = bf2f(t4.x); qs[rr][seg + 1] = bf2f(t4.y);
        qs[rr][seg + 2] = bf2f(t4.z); qs[rr][seg + 3] = bf2f(t4.w);
    }
    __syncthreads();

    float acc[8] = {0.f, 0.f, 0.f, 0.f, 0.f, 0.f, 0.f, 0.f};
    float mrow = -INFINITY, lrow = 0.f;
    const int d0 = q8 * 8;

    for (int j0 = 0; j0 < SEQ; j0 += 64) {
        for (int i = tid; i < 64 * 16; i += 256) {
            int rr = i >> 4, seg = (i & 15) * 4;
            ushort4 k4 = *(const ushort4*)&kws[base_nh + (size_t)(j0 + rr) * DH + seg];
            ushort4 v4 = *(const ushort4*)&vws[base_nh + (size_t)(j0 + rr) * DH + seg];
            ks[rr][seg + 0] = bf2f(k4.x); ks[rr][seg + 1] = bf2f(k4.y);
            ks[rr][seg + 2] = bf2f(k4.z); ks[rr][seg + 3] = bf2f(k4.w);
            vs[rr][seg + 0] = bf2f(v4.x); vs[rr][seg + 1] = bf2f(v4.y);
            vs[rr][seg + 2] = bf2f(v4.z); vs[rr][seg + 3] = bf2f(v4.w);
        }
        __syncthreads();

        float s[8];
#pragma unroll
        for (int jj = 0; jj < 8; ++jj) s[jj] = 0.f;
#pragma unroll
        for (int d4 = 0; d4 < 16; ++d4) {
            float4 qv = *(const float4*)&qs[r][d4 * 4];
#pragma unroll
            for (int jj = 0; jj < 8; ++jj) {
                int j = jj * 8 + q8;
                float4 kv = *(const float4*)&ks[j][d4 * 4];
                s[jj] += qv.x * kv.x + qv.y * kv.y + qv.z * kv.z + qv.w * kv.w;
            }
        }
#pragma unroll
        for (int jj = 0; jj < 8; ++jj) {
            int j = jj * 8 + q8;
            size_t midx = ((size_t)n * SEQ + i0 + r) * SEQ + j0 + j;
            int mv = mask_is_int ? ((const int*)mask)[midx]
                                 : (int)((const unsigned char*)mask)[midx];
            s[jj] = mv ? -1e9f : s[jj] * 0.125f;  // reference order: mask unscaled
        }

        float tmax = s[0];
#pragma unroll
        for (int jj = 1; jj < 8; ++jj) tmax = fmaxf(tmax, s[jj]);
        for (int o = 1; o < 8; o <<= 1) tmax = fmaxf(tmax, __shfl_xor(tmax, o));

        float newm = fmaxf(mrow, tmax);
        float corr = __expf(mrow - newm);  // first tile: exp(-inf) = 0
        float lsum = 0.f;
#pragma unroll
        for (int jj = 0; jj < 8; ++jj) {
            float p = __expf(s[jj] - newm);
            ps[r][jj * 8 + q8] = p;
            lsum += p;
        }
        for (int o = 1; o < 8; o <<= 1) lsum += __shfl_xor(lsum, o);
        lrow = lrow * corr + lsum;
        mrow = newm;
#pragma unroll
        for (int dd = 0; dd < 8; ++dd) acc[dd] *= corr;
        __syncthreads();

#pragma unroll 8
        for (int j = 0; j < 64; ++j) {
            float pj = ps[r][j];
            float4 v0 = *(const float4*)&vs[j][d0];
            float4 v1 = *(const float4*)&vs[j][d0 + 4];
            acc[0] += pj * v0.x; acc[1] += pj * v0.y;
            acc[2] += pj * v0.z; acc[3] += pj * v0.w;
            acc[4] += pj * v1.x; acc[5] += pj * v1.y;
            acc[6] += pj * v1.z; acc[7] += pj * v1.w;
        }
        __syncthreads();
    }

    float inv = 1.f / lrow;
#pragma unroll
    for (int dd = 0; dd < 8; ++dd) {
        yws[((size_t)n * SEQ + i0 + r) * DMODEL + h * DH + d0 + dd] =
            f2bf(acc[dd] * inv);
    }
}

// ---------------------------------------------------------------------------
// Output projection: out[r][c] = sum_m Y[r][m] * Wp[m][c] + bp[c]
// ---------------------------------------------------------------------------
__global__ __launch_bounds__(256) void out_gemm(
    const unsigned short* __restrict__ Y, const void* __restrict__ Wp,
    const void* __restrict__ bp, void* __restrict__ out,
    const int* __restrict__ flags)
{
    const int isbf = flags[0];
    const int c0 = blockIdx.x * 64;
    const int r0 = blockIdx.y * 64;
    const int tid = threadIdx.x;
    const int tx = tid & 15, ty = tid >> 4;

    __shared__ float As[32][68];
    __shared__ float Bs[32][68];

    float acc[4][4] = {};

    for (int m0 = 0; m0 < DMODEL; m0 += 32) {
        for (int i = tid; i < 64 * 32; i += 256) {
            int r = i >> 5, m = i & 31;
            As[m][r] = bf2f(Y[(size_t)(r0 + r) * DMODEL + m0 + m]);
        }
        for (int i = tid; i < 32 * 64; i += 256) {
            int m = i >> 6, c = i & 63;
            Bs[m][c] = ldin(Wp, (size_t)(m0 + m) * DIN + c0 + c, isbf);
        }
        __syncthreads();
#pragma unroll
        for (int mm = 0; mm < 32; ++mm) {
            float4 a4 = *(const float4*)&As[mm][ty * 4];
            float4 b4 = *(const float4*)&Bs[mm][tx * 4];
            float av[4] = {a4.x, a4.y, a4.z, a4.w};
            float bvv[4] = {b4.x, b4.y, b4.z, b4.w};
#pragma unroll
            for (int i = 0; i < 4; ++i)
#pragma unroll
                for (int j = 0; j < 4; ++j) acc[i][j] += av[i] * bvv[j];
        }
        __syncthreads();
    }

#pragma unroll
    for (int i = 0; i < 4; ++i) {
        int r = r0 + ty * 4 + i;
#pragma unroll
        for (int j = 0; j < 4; ++j) {
            int c = c0 + tx * 4 + j;
            float b = ldin(bp, c, isbf);
            float v = acc[i][j] + b;
            size_t oidx = (size_t)r * DIN + c;
            if (isbf) ((unsigned short*)out)[oidx] = f2bf(v);
            else      ((float*)out)[oidx] = v;
        }
    }
}

extern "C" void kernel_launch(void* const* d_in, const int* in_sizes, int n_in,
                              void* d_out, int out_size, void* d_ws, size_t ws_size,
                              hipStream_t stream) {
    const void* query = d_in[0];
    const void* key_  = d_in[1];
    const void* value = d_in[2];
    const void* mask  = d_in[3];
    const void* Wq = d_in[4];
    const void* bq = d_in[5];
    const void* Wk = d_in[6];
    const void* bk = d_in[7];
    const void* Wv = d_in[8];
    const void* bv = d_in[9];
    const void* Wp = d_in[10];
    const void* bp = d_in[11];

    // workspace: bf16 q,k,v (n,h,k,d) + bf16 y (n,k,dmodel) + flags
    const size_t per = (size_t)NB * NH * SEQ * DH;  // 4M elems
    unsigned short* qws = (unsigned short*)d_ws;
    unsigned short* kws = qws + per;
    unsigned short* vws = kws + per;
    unsigned short* yws = vws + per;
    int* flags = (int*)(yws + per);   // 33.5 MB + 8 B total

    detect<<<1, 256, 0, stream>>>((const unsigned short*)query, (const int*)mask, flags);
    proj_gemm<<<dim3(NH, 64, 3), 256, 0, stream>>>(query, key_, value,
                                                   Wq, bq, Wk, bk, Wv, bv,
                                                   qws, kws, vws, flags);
    attn<<<dim3(SEQ / 32, NH, NB), 256, 0, stream>>>(qws, kws, vws, mask, yws, flags);
    out_gemm<<<dim3(DIN / 64, 64), 256, 0, stream>>>(yws, Wp, bp, d_out, flags);
}

// Round 4
// 944.579 us; speedup vs baseline: 4.1371x; 4.1371x over previous
//
#include <hip/hip_runtime.h>
#include <hip/hip_bf16.h>

typedef __attribute__((ext_vector_type(8))) __bf16 bf16x8;
typedef __attribute__((ext_vector_type(4))) float floatx4;

#define NB 2
#define SEQ 2048
#define DIN 1024
#define NH 16
#define DH 64
#define DMODEL 1024  // NH*DH
#define BQ 128
#define BK 64
#define PAD 72       // bf16 LDS row stride: 144 B, 16B-aligned, 2-way banks only

__device__ __forceinline__ float bf2f(unsigned short u) {
    return __uint_as_float(((unsigned)u) << 16);
}
__device__ __forceinline__ unsigned short f2bf(float f) {
    unsigned u = __float_as_uint(f);
    unsigned r = (u + 0x7FFFu + ((u >> 16) & 1u)) >> 16;  // RNE
    return (unsigned short)r;
}
__device__ __forceinline__ float ldin(const void* p, size_t idx, int isbf) {
    return isbf ? bf2f(((const unsigned short*)p)[idx]) : ((const float*)p)[idx];
}

// ---------------------------------------------------------------------------
// dtype detector (proven r3): flags[0]=inputs-are-bf16, flags[1]=mask-is-int32
// ---------------------------------------------------------------------------
__global__ void detect(const unsigned short* q, const int* mask_i, int* flags) {
    __shared__ int cnt[2];
    int t = threadIdx.x;
    if (t < 2) cnt[t] = 0;
    __syncthreads();
    unsigned short u = q[2 * t];
    int e = (u >> 7) & 0xFF;
    int sane = (u == 0 || (e > 100 && e < 140)) ? 1 : 0;
    int v = mask_i[t];
    int zo = (v == 0 || v == 1) ? 1 : 0;
    atomicAdd(&cnt[0], sane);
    atomicAdd(&cnt[1], zo);
    __syncthreads();
    if (t == 0) {
        flags[0] = (cnt[0] >= 160) ? 1 : 0;
        flags[1] = (cnt[1] >= 230) ? 1 : 0;
    }
}

// ---------------------------------------------------------------------------
// mask -> 1 bit per entry. word w covers keys [w*32, w*32+32) of row n,q.
// bit=1 means masked (score := -1e9).
// ---------------------------------------------------------------------------
__global__ __launch_bounds__(256) void mask_pack(const void* __restrict__ mask,
                                                 unsigned int* __restrict__ mbits,
                                                 const int* __restrict__ flags) {
    const int is_int = flags[1];
    int w = blockIdx.x * 256 + threadIdx.x;  // 0 .. 2*2048*64-1
    unsigned bits = 0;
    if (is_int) {
        const int4* p = (const int4*)mask + (size_t)w * 8;
#pragma unroll
        for (int g = 0; g < 8; ++g) {
            int4 v = p[g];
            bits |= (unsigned)(v.x != 0) << (g * 4 + 0);
            bits |= (unsigned)(v.y != 0) << (g * 4 + 1);
            bits |= (unsigned)(v.z != 0) << (g * 4 + 2);
            bits |= (unsigned)(v.w != 0) << (g * 4 + 3);
        }
    } else {
        const uint4* p = (const uint4*)mask + (size_t)w * 2;
#pragma unroll
        for (int g = 0; g < 2; ++g) {
            uint4 v = p[g];
            unsigned ws4[4] = {v.x, v.y, v.z, v.w};
#pragma unroll
            for (int c = 0; c < 4; ++c)
#pragma unroll
                for (int b = 0; b < 4; ++b)
                    bits |= (unsigned)(((ws4[c] >> (8 * b)) & 0xFFu) != 0)
                            << (g * 16 + c * 4 + b);
        }
    }
    mbits[w] = bits;
}

// ---------------------------------------------------------------------------
// Projection GEMM (unchanged r3 structure). z==2 (V) writes TRANSPOSED:
// vt[n,h,d,k] so attention PV B-fragments are key-contiguous.
// ---------------------------------------------------------------------------
__global__ __launch_bounds__(256) void proj_gemm(
    const void* __restrict__ Aq, const void* __restrict__ Ak, const void* __restrict__ Av,
    const void* __restrict__ Wq, const void* __restrict__ bq,
    const void* __restrict__ Wk, const void* __restrict__ bk,
    const void* __restrict__ Wv, const void* __restrict__ bv,
    unsigned short* __restrict__ qws, unsigned short* __restrict__ kws,
    unsigned short* __restrict__ vtws, const int* __restrict__ flags)
{
    const int isbf = flags[0];
    const int z = blockIdx.z;
    const void* A    = (z == 0) ? Aq : (z == 1) ? Ak : Av;
    const void* W    = (z == 0) ? Wq : (z == 1) ? Wk : Wv;
    const void* bias = (z == 0) ? bq : (z == 1) ? bk : bv;
    unsigned short* C = (z == 0) ? qws : (z == 1) ? kws : vtws;

    const int h  = blockIdx.x;
    const int c0 = h * 64;
    const int r0 = blockIdx.y * 64;
    const int tid = threadIdx.x;
    const int tx = tid & 15, ty = tid >> 4;

    __shared__ float As[32][68];
    __shared__ float Bs[32][68];

    float acc[4][4] = {};

    for (int m0 = 0; m0 < DIN; m0 += 32) {
        for (int i = tid; i < 64 * 32; i += 256) {
            int r = i >> 5, m = i & 31;
            As[m][r] = ldin(A, (size_t)(r0 + r) * DIN + m0 + m, isbf);
        }
        for (int i = tid; i < 32 * 64; i += 256) {
            int m = i >> 6, c = i & 63;
            Bs[m][c] = ldin(W, (size_t)h * DIN * DH + (size_t)(m0 + m) * DH + c, isbf);
        }
        __syncthreads();
#pragma unroll
        for (int mm = 0; mm < 32; ++mm) {
            float4 a4 = *(const float4*)&As[mm][ty * 4];
            float4 b4 = *(const float4*)&Bs[mm][tx * 4];
            float av[4] = {a4.x, a4.y, a4.z, a4.w};
            float bvv[4] = {b4.x, b4.y, b4.z, b4.w};
#pragma unroll
            for (int i = 0; i < 4; ++i)
#pragma unroll
                for (int j = 0; j < 4; ++j) acc[i][j] += av[i] * bvv[j];
        }
        __syncthreads();
    }

#pragma unroll
    for (int i = 0; i < 4; ++i) {
        int r = r0 + ty * 4 + i;
        int n = r >> 11, k = r & (SEQ - 1);
#pragma unroll
        for (int j = 0; j < 4; ++j) {
            int c = c0 + tx * 4 + j;
            int d = c & 63;
            float b = ldin(bias, c, isbf);
            unsigned short val = f2bf(acc[i][j] + b);
            if (z == 2)
                C[(((size_t)n * NH + h) * DH + d) * SEQ + k] = val;           // V^T
            else
                C[(((size_t)n * NH + h) * SEQ + k) * DH + d] = val;           // row-major
        }
    }
}

// ---------------------------------------------------------------------------
// MFMA flash attention. Block = (n, h, 128 q-rows), 4 waves x 32 rows.
// 16x16x32 bf16 MFMA. Online softmax in C-layout regs; P via per-wave LDS.
// ---------------------------------------------------------------------------
__global__ __launch_bounds__(256) void attn_mfma(
    const unsigned short* __restrict__ qws, const unsigned short* __restrict__ kws,
    const unsigned short* __restrict__ vtws, const unsigned int* __restrict__ mbits,
    unsigned short* __restrict__ yws)
{
    const int qt   = blockIdx.x;   // 0..15
    const int h    = blockIdx.y;   // 0..15
    const int n    = blockIdx.z;   // 0..1
    const int tid  = threadIdx.x;
    const int wave = tid >> 6;
    const int lane = tid & 63;
    const int l16  = lane & 15;
    const int quad = lane >> 4;

    __shared__ __align__(16) unsigned short Qs[BQ * PAD];      // [qrow][d]
    __shared__ __align__(16) unsigned short Ks[BK * PAD];      // [key][d]
    __shared__ __align__(16) unsigned short VTs[DH * PAD];     // [d][key]
    __shared__ __align__(16) unsigned short Ps[4][32 * PAD];   // per-wave [row][key]
    __shared__ unsigned int Ms[BQ][2];                         // mask bits

    const size_t base_nh = ((size_t)n * NH + h) * SEQ * DH;
    const size_t base_vt = ((size_t)n * NH + h) * DH * SEQ;
    const int q0 = qt * BQ;
    const unsigned int* mrow_base = mbits + ((size_t)n * SEQ + q0) * (SEQ / 32);

    // stage Q once
    for (int i = tid; i < BQ * 8; i += 256) {
        int row = i >> 3, seg = (i & 7) * 8;
        *(bf16x8*)&Qs[row * PAD + seg] =
            *(const bf16x8*)&qws[base_nh + (size_t)(q0 + row) * DH + seg];
    }
    __syncthreads();

    // Q fragments are loop-invariant: A[m=l16][k=quad*8+j (+32)]
    bf16x8 af[2][2];
#pragma unroll
    for (int mt = 0; mt < 2; ++mt)
#pragma unroll
        for (int ks = 0; ks < 2; ++ks)
            af[mt][ks] = *(const bf16x8*)&Qs[(wave * 32 + mt * 16 + l16) * PAD + ks * 32 + quad * 8];

    floatx4 O[2][4];
#pragma unroll
    for (int mt = 0; mt < 2; ++mt)
#pragma unroll
        for (int dt = 0; dt < 4; ++dt) O[mt][dt] = floatx4{0.f, 0.f, 0.f, 0.f};
    float mrow[2][4], lrow[2][4];
#pragma unroll
    for (int mt = 0; mt < 2; ++mt)
#pragma unroll
        for (int r = 0; r < 4; ++r) { mrow[mt][r] = -INFINITY; lrow[mt][r] = 0.f; }

    for (int j0 = 0; j0 < SEQ; j0 += BK) {
        // stage K tile [64 keys][64 d]
        for (int i = tid; i < BK * 8; i += 256) {
            int row = i >> 3, seg = (i & 7) * 8;
            *(bf16x8*)&Ks[row * PAD + seg] =
                *(const bf16x8*)&kws[base_nh + (size_t)(j0 + row) * DH + seg];
        }
        // stage V^T tile [64 d][64 keys]
        for (int i = tid; i < DH * 8; i += 256) {
            int dr = i >> 3, seg = (i & 7) * 8;
            *(bf16x8*)&VTs[dr * PAD + seg] =
                *(const bf16x8*)&vtws[base_vt + (size_t)dr * SEQ + j0 + seg];
        }
        // stage mask bits: 128 rows x 2 words
        {
            int row = tid >> 1, w = tid & 1;
            Ms[row][w] = mrow_base[(size_t)row * (SEQ / 32) + (j0 >> 5) + w];
        }
        __syncthreads();

        // ---- QK^T ----
        bf16x8 bfK[4][2];
#pragma unroll
        for (int nt = 0; nt < 4; ++nt)
#pragma unroll
            for (int ks = 0; ks < 2; ++ks)
                bfK[nt][ks] = *(const bf16x8*)&Ks[(nt * 16 + l16) * PAD + ks * 32 + quad * 8];

        float S[2][4][4];
#pragma unroll
        for (int mt = 0; mt < 2; ++mt)
#pragma unroll
            for (int nt = 0; nt < 4; ++nt) {
                floatx4 c = {0.f, 0.f, 0.f, 0.f};
                c = __builtin_amdgcn_mfma_f32_16x16x32_bf16(af[mt][0], bfK[nt][0], c, 0, 0, 0);
                c = __builtin_amdgcn_mfma_f32_16x16x32_bf16(af[mt][1], bfK[nt][1], c, 0, 0, 0);
                S[mt][nt][0] = c[0]; S[mt][nt][1] = c[1];
                S[mt][nt][2] = c[2]; S[mt][nt][3] = c[3];
            }

        // ---- mask + scale (reference order: masked := exactly -1e9) ----
#pragma unroll
        for (int mt = 0; mt < 2; ++mt)
#pragma unroll
            for (int r = 0; r < 4; ++r) {
                int lrowi = wave * 32 + mt * 16 + quad * 4 + r;
#pragma unroll
                for (int nt = 0; nt < 4; ++nt) {
                    unsigned w = Ms[lrowi][nt >> 1];
                    int bit = (w >> ((nt & 1) * 16 + l16)) & 1;
                    S[mt][nt][r] = bit ? -1e9f : S[mt][nt][r] * 0.125f;
                }
            }

        // ---- online softmax (m row-reduced; l kept per-lane, reduced at end) ----
#pragma unroll
        for (int mt = 0; mt < 2; ++mt)
#pragma unroll
            for (int r = 0; r < 4; ++r) {
                float mx = S[mt][0][r];
#pragma unroll
                for (int nt = 1; nt < 4; ++nt) mx = fmaxf(mx, S[mt][nt][r]);
                for (int o = 1; o < 16; o <<= 1) mx = fmaxf(mx, __shfl_xor(mx, o));
                float mnew = fmaxf(mrow[mt][r], mx);
                float alpha = __expf(mrow[mt][r] - mnew);
                mrow[mt][r] = mnew;
                float ls = 0.f;
#pragma unroll
                for (int nt = 0; nt < 4; ++nt) {
                    float p = __expf(S[mt][nt][r] - mnew);
                    S[mt][nt][r] = p;
                    ls += p;
                }
                lrow[mt][r] = lrow[mt][r] * alpha + ls;
#pragma unroll
                for (int dt = 0; dt < 4; ++dt) O[mt][dt][r] *= alpha;
            }

        // ---- P -> per-wave LDS (bf16) ----
#pragma unroll
        for (int mt = 0; mt < 2; ++mt)
#pragma unroll
            for (int nt = 0; nt < 4; ++nt)
#pragma unroll
                for (int r = 0; r < 4; ++r)
                    Ps[wave][(mt * 16 + quad * 4 + r) * PAD + nt * 16 + l16] = f2bf(S[mt][nt][r]);

        // ---- PV ----
        bf16x8 pa[2][2], vb[4][2];
#pragma unroll
        for (int mt = 0; mt < 2; ++mt)
#pragma unroll
            for (int ks = 0; ks < 2; ++ks)
                pa[mt][ks] = *(const bf16x8*)&Ps[wave][(mt * 16 + l16) * PAD + ks * 32 + quad * 8];
#pragma unroll
        for (int dt = 0; dt < 4; ++dt)
#pragma unroll
            for (int ks = 0; ks < 2; ++ks)
                vb[dt][ks] = *(const bf16x8*)&VTs[(dt * 16 + l16) * PAD + ks * 32 + quad * 8];
#pragma unroll
        for (int mt = 0; mt < 2; ++mt)
#pragma unroll
            for (int dt = 0; dt < 4; ++dt) {
                O[mt][dt] = __builtin_amdgcn_mfma_f32_16x16x32_bf16(pa[mt][0], vb[dt][0], O[mt][dt], 0, 0, 0);
                O[mt][dt] = __builtin_amdgcn_mfma_f32_16x16x32_bf16(pa[mt][1], vb[dt][1], O[mt][dt], 0, 0, 0);
            }
        __syncthreads();
    }

    // epilogue: reduce l across the 16 lanes of each row, normalize, store
#pragma unroll
    for (int mt = 0; mt < 2; ++mt)
#pragma unroll
        for (int r = 0; r < 4; ++r)
            for (int o = 1; o < 16; o <<= 1) lrow[mt][r] += __shfl_xor(lrow[mt][r], o);

#pragma unroll
    for (int mt = 0; mt < 2; ++mt)
#pragma unroll
        for (int r = 0; r < 4; ++r) {
            int row = q0 + wave * 32 + mt * 16 + quad * 4 + r;
            float inv = 1.f / lrow[mt][r];
#pragma unroll
            for (int dt = 0; dt < 4; ++dt) {
                int col = h * DH + dt * 16 + l16;
                yws[((size_t)n * SEQ + row) * DMODEL + col] = f2bf(O[mt][dt][r] * inv);
            }
        }
}

// ---------------------------------------------------------------------------
// Output projection (unchanged r3)
// ---------------------------------------------------------------------------
__global__ __launch_bounds__(256) void out_gemm(
    const unsigned short* __restrict__ Y, const void* __restrict__ Wp,
    const void* __restrict__ bp, void* __restrict__ out,
    const int* __restrict__ flags)
{
    const int isbf = flags[0];
    const int c0 = blockIdx.x * 64;
    const int r0 = blockIdx.y * 64;
    const int tid = threadIdx.x;
    const int tx = tid & 15, ty = tid >> 4;

    __shared__ float As[32][68];
    __shared__ float Bs[32][68];

    float acc[4][4] = {};

    for (int m0 = 0; m0 < DMODEL; m0 += 32) {
        for (int i = tid; i < 64 * 32; i += 256) {
            int r = i >> 5, m = i & 31;
            As[m][r] = bf2f(Y[(size_t)(r0 + r) * DMODEL + m0 + m]);
        }
        for (int i = tid; i < 32 * 64; i += 256) {
            int m = i >> 6, c = i & 63;
            Bs[m][c] = ldin(Wp, (size_t)(m0 + m) * DIN + c0 + c, isbf);
        }
        __syncthreads();
#pragma unroll
        for (int mm = 0; mm < 32; ++mm) {
            float4 a4 = *(const float4*)&As[mm][ty * 4];
            float4 b4 = *(const float4*)&Bs[mm][tx * 4];
            float av[4] = {a4.x, a4.y, a4.z, a4.w};
            float bvv[4] = {b4.x, b4.y, b4.z, b4.w};
#pragma unroll
            for (int i = 0; i < 4; ++i)
#pragma unroll
                for (int j = 0; j < 4; ++j) acc[i][j] += av[i] * bvv[j];
        }
        __syncthreads();
    }

#pragma unroll
    for (int i = 0; i < 4; ++i) {
        int r = r0 + ty * 4 + i;
#pragma unroll
        for (int j = 0; j < 4; ++j) {
            int c = c0 + tx * 4 + j;
            float b = ldin(bp, c, isbf);
            float v = acc[i][j] + b;
            size_t oidx = (size_t)r * DIN + c;
            if (isbf) ((unsigned short*)out)[oidx] = f2bf(v);
            else      ((float*)out)[oidx] = v;
        }
    }
}

extern "C" void kernel_launch(void* const* d_in, const int* in_sizes, int n_in,
                              void* d_out, int out_size, void* d_ws, size_t ws_size,
                              hipStream_t stream) {
    const void* query = d_in[0];
    const void* key_  = d_in[1];
    const void* value = d_in[2];
    const void* mask  = d_in[3];
    const void* Wq = d_in[4];
    const void* bq = d_in[5];
    const void* Wk = d_in[6];
    const void* bk = d_in[7];
    const void* Wv = d_in[8];
    const void* bv = d_in[9];
    const void* Wp = d_in[10];
    const void* bp = d_in[11];

    // ws: q,k (n,h,k,d) + v^T (n,h,d,k) + y (n,k,dmodel), all bf16; mask bits; flags
    const size_t per = (size_t)NB * NH * SEQ * DH;  // 4M elems
    unsigned short* qws = (unsigned short*)d_ws;
    unsigned short* kws = qws + per;
    unsigned short* vtws = kws + per;
    unsigned short* yws = vtws + per;
    unsigned int* mbits = (unsigned int*)(yws + per);           // 2*2048*64 words = 1 MB
    int* flags = (int*)(mbits + (size_t)NB * SEQ * (SEQ / 32)); // +8 B

    detect<<<1, 256, 0, stream>>>((const unsigned short*)query, (const int*)mask, flags);
    mask_pack<<<(NB * SEQ * (SEQ / 32)) / 256, 256, 0, stream>>>(mask, mbits, flags);
    proj_gemm<<<dim3(NH, 64, 3), 256, 0, stream>>>(query, key_, value,
                                                   Wq, bq, Wk, bk, Wv, bv,
                                                   qws, kws, vtws, flags);
    attn_mfma<<<dim3(SEQ / BQ, NH, NB), 256, 0, stream>>>(qws, kws, vtws, mbits, yws);
    out_gemm<<<dim3(DIN / 64, 64), 256, 0, stream>>>(yws, Wp, bp, d_out, flags);
}

// Round 5
// 383.144 us; speedup vs baseline: 10.1994x; 2.4653x over previous
//
#include <hip/hip_runtime.h>
#include <hip/hip_bf16.h>

typedef __attribute__((ext_vector_type(8))) __bf16 bf16x8;
typedef __attribute__((ext_vector_type(4))) float floatx4;

#define NB 2
#define SEQ 2048
#define DIN 1024
#define NH 16
#define DH 64
#define DMODEL 1024  // NH*DH
#define BQ 128
#define BK 64
#define PAD 72       // attn LDS row stride

__device__ __forceinline__ float bf2f(unsigned short u) {
    return __uint_as_float(((unsigned)u) << 16);
}
__device__ __forceinline__ unsigned short f2bf(float f) {
    unsigned u = __float_as_uint(f);
    unsigned r = (u + 0x7FFFu + ((u >> 16) & 1u)) >> 16;  // RNE
    return (unsigned short)r;
}
__device__ __forceinline__ float ldin(const void* p, size_t idx, int isbf) {
    return isbf ? bf2f(((const unsigned short*)p)[idx]) : ((const float*)p)[idx];
}

// ---------------------------------------------------------------------------
// dtype detector (proven r3): flags[0]=inputs-are-bf16, flags[1]=mask-is-int32
// ---------------------------------------------------------------------------
__global__ void detect(const unsigned short* q, const int* mask_i, int* flags) {
    __shared__ int cnt[2];
    int t = threadIdx.x;
    if (t < 2) cnt[t] = 0;
    __syncthreads();
    unsigned short u = q[2 * t];
    int e = (u >> 7) & 0xFF;
    int sane = (u == 0 || (e > 100 && e < 140)) ? 1 : 0;
    int v = mask_i[t];
    int zo = (v == 0 || v == 1) ? 1 : 0;
    atomicAdd(&cnt[0], sane);
    atomicAdd(&cnt[1], zo);
    __syncthreads();
    if (t == 0) {
        flags[0] = (cnt[0] >= 160) ? 1 : 0;
        flags[1] = (cnt[1] >= 230) ? 1 : 0;
    }
}

// ---------------------------------------------------------------------------
// activations fp32->bf16 (or bf16 copy), coalesced
// ---------------------------------------------------------------------------
__global__ __launch_bounds__(256) void conv_a(
    const void* __restrict__ q, const void* __restrict__ k, const void* __restrict__ v,
    unsigned short* __restrict__ a0, unsigned short* __restrict__ a1,
    unsigned short* __restrict__ a2, const int* __restrict__ flags)
{
    const int isbf = flags[0];
    const int z = blockIdx.z;
    const void* src = (z == 0) ? q : (z == 1) ? k : v;
    unsigned short* dst = (z == 0) ? a0 : (z == 1) ? a1 : a2;
    size_t i = ((size_t)blockIdx.x * 256 + threadIdx.x) * 4;
    if (isbf) {
        *(ushort4*)&dst[i] = *(const ushort4*)((const unsigned short*)src + i);
    } else {
        float4 f = *(const float4*)((const float*)src + i);
        ushort4 o;
        o.x = f2bf(f.x); o.y = f2bf(f.y); o.z = f2bf(f.z); o.w = f2bf(f.w);
        *(ushort4*)&dst[i] = o;
    }
}

// ---------------------------------------------------------------------------
// weights -> transposed bf16 WT[c][m] (1024x1024). z<3: W(h,m,d), c=h*64+d.
// z==3: Wp(m,c). Writes coalesced in m; reads strided (L2-absorbed, 4 MB).
// ---------------------------------------------------------------------------
__global__ __launch_bounds__(256) void conv_w(
    const void* __restrict__ wq, const void* __restrict__ wk,
    const void* __restrict__ wv, const void* __restrict__ wp,
    unsigned short* __restrict__ t0, unsigned short* __restrict__ t1,
    unsigned short* __restrict__ t2, unsigned short* __restrict__ t3,
    const int* __restrict__ flags)
{
    const int isbf = flags[0];
    const int z = blockIdx.z;
    const void* src = (z == 0) ? wq : (z == 1) ? wk : (z == 2) ? wv : wp;
    unsigned short* dst = (z == 0) ? t0 : (z == 1) ? t1 : (z == 2) ? t2 : t3;
    int idx = blockIdx.x * 256 + threadIdx.x;  // [c][m]
    int m = idx & 1023, c = idx >> 10;
    size_t sidx;
    if (z < 3) { int h = c >> 6, d = c & 63; sidx = (size_t)h * 65536 + (size_t)m * 64 + d; }
    else       { sidx = (size_t)m * 1024 + c; }
    dst[idx] = f2bf(ldin(src, sidx, isbf));
}

// ---------------------------------------------------------------------------
// mask -> 1 bit per entry (proven r4)
// ---------------------------------------------------------------------------
__global__ __launch_bounds__(256) void mask_pack(const void* __restrict__ mask,
                                                 unsigned int* __restrict__ mbits,
                                                 const int* __restrict__ flags) {
    const int is_int = flags[1];
    int w = blockIdx.x * 256 + threadIdx.x;
    unsigned bits = 0;
    if (is_int) {
        const int4* p = (const int4*)mask + (size_t)w * 8;
#pragma unroll
        for (int g = 0; g < 8; ++g) {
            int4 v = p[g];
            bits |= (unsigned)(v.x != 0) << (g * 4 + 0);
            bits |= (unsigned)(v.y != 0) << (g * 4 + 1);
            bits |= (unsigned)(v.z != 0) << (g * 4 + 2);
            bits |= (unsigned)(v.w != 0) << (g * 4 + 3);
        }
    } else {
        const uint4* p = (const uint4*)mask + (size_t)w * 2;
#pragma unroll
        for (int g = 0; g < 2; ++g) {
            uint4 v = p[g];
            unsigned ws4[4] = {v.x, v.y, v.z, v.w};
#pragma unroll
            for (int c = 0; c < 4; ++c)
#pragma unroll
                for (int b = 0; b < 4; ++b)
                    bits |= (unsigned)(((ws4[c] >> (8 * b)) & 0xFFu) != 0)
                            << (g * 16 + c * 4 + b);
        }
    }
    mbits[w] = bits;
}

// ---------------------------------------------------------------------------
// Unified MFMA GEMM: C(4096x1024) = A(4096x1024,bf16) x BT(1024x1024,bf16)^T
// + bias. 128x128 tile, BK=64, 4 waves x (64x64). mode = mode0+z:
//   0/1: Q/K -> ws (n,h,k,d); 2: V -> ws^T (n,h,d,k) via LDS transpose;
//   3: OUT row-major (fp32 or bf16 by flag).
// ---------------------------------------------------------------------------
__global__ __launch_bounds__(256) void gemm_mfma(
    const unsigned short* __restrict__ A0, const unsigned short* __restrict__ A1,
    const unsigned short* __restrict__ A2,
    const unsigned short* __restrict__ B0, const unsigned short* __restrict__ B1,
    const unsigned short* __restrict__ B2,
    const void* __restrict__ bias0, const void* __restrict__ bias1,
    const void* __restrict__ bias2,
    void* __restrict__ C0, void* __restrict__ C1, void* __restrict__ C2,
    int mode0, const int* __restrict__ flags)
{
    const int z = blockIdx.z;
    const unsigned short* A  = (z == 0) ? A0 : (z == 1) ? A1 : A2;
    const unsigned short* BT = (z == 0) ? B0 : (z == 1) ? B1 : B2;
    const void* bias = (z == 0) ? bias0 : (z == 1) ? bias1 : bias2;
    void* C = (z == 0) ? C0 : (z == 1) ? C1 : C2;
    const int mode = mode0 + z;
    const int isbf = flags[0];

    const int n0  = blockIdx.x * 128;
    const int m0g = blockIdx.y * 128;
    const int tid = threadIdx.x;
    const int wave = tid >> 6, lane = tid & 63;
    const int l16 = lane & 15, quad = lane >> 4;
    const int wm = wave & 1, wn = wave >> 1;

    __shared__ __align__(16) unsigned short smem[17408];  // As(8192)+Bs(8192); V-epilogue Ts(128x136)
    unsigned short* As = smem;
    unsigned short* Bs = smem + 8192;

    floatx4 acc[4][4];
#pragma unroll
    for (int mt = 0; mt < 4; ++mt)
#pragma unroll
        for (int nt = 0; nt < 4; ++nt) acc[mt][nt] = floatx4{0.f, 0.f, 0.f, 0.f};

    for (int kk = 0; kk < 1024; kk += 64) {
#pragma unroll
        for (int j = 0; j < 4; ++j) {
            int i = tid + j * 256;
            int row = i >> 3, seg = (i & 7) * 8;
            *(bf16x8*)&As[row * 64 + seg] = *(const bf16x8*)&A[(size_t)(m0g + row) * 1024 + kk + seg];
            *(bf16x8*)&Bs[row * 64 + seg] = *(const bf16x8*)&BT[(size_t)(n0 + row) * 1024 + kk + seg];
        }
        __syncthreads();
#pragma unroll
        for (int ks = 0; ks < 2; ++ks) {
            bf16x8 af[4], bf[4];
#pragma unroll
            for (int mt = 0; mt < 4; ++mt)
                af[mt] = *(const bf16x8*)&As[(wm * 64 + mt * 16 + l16) * 64 + ks * 32 + quad * 8];
#pragma unroll
            for (int nt = 0; nt < 4; ++nt)
                bf[nt] = *(const bf16x8*)&Bs[(wn * 64 + nt * 16 + l16) * 64 + ks * 32 + quad * 8];
#pragma unroll
            for (int mt = 0; mt < 4; ++mt)
#pragma unroll
                for (int nt = 0; nt < 4; ++nt)
                    acc[mt][nt] = __builtin_amdgcn_mfma_f32_16x16x32_bf16(af[mt], bf[nt], acc[mt][nt], 0, 0, 0);
        }
        __syncthreads();
    }

    float bv4[4];
#pragma unroll
    for (int nt = 0; nt < 4; ++nt)
        bv4[nt] = ldin(bias, n0 + wn * 64 + nt * 16 + l16, isbf);

    if (mode <= 1) {  // Q/K -> (n,h,k,d)
        unsigned short* O = (unsigned short*)C;
#pragma unroll
        for (int mt = 0; mt < 4; ++mt)
#pragma unroll
            for (int reg = 0; reg < 4; ++reg) {
                int row = m0g + wm * 64 + mt * 16 + quad * 4 + reg;
                int nb = row >> 11, kq = row & (SEQ - 1);
#pragma unroll
                for (int nt = 0; nt < 4; ++nt) {
                    int c = n0 + wn * 64 + nt * 16 + l16;
                    int h = c >> 6, d = c & 63;
                    O[(((size_t)nb * NH + h) * SEQ + kq) * DH + d] = f2bf(acc[mt][nt][reg] + bv4[nt]);
                }
            }
    } else if (mode == 2) {  // V -> (n,h,d,k), coalesced via LDS transpose
#pragma unroll
        for (int mt = 0; mt < 4; ++mt)
#pragma unroll
            for (int nt = 0; nt < 4; ++nt)
#pragma unroll
                for (int reg = 0; reg < 4; ++reg) {
                    int m_l = wm * 64 + mt * 16 + quad * 4 + reg;
                    int c_l = wn * 64 + nt * 16 + l16;
                    smem[c_l * 136 + m_l] = f2bf(acc[mt][nt][reg] + bv4[nt]);
                }
        __syncthreads();
        unsigned short* O = (unsigned short*)C;
        int nb = m0g >> 11;
        int kq0 = m0g & (SEQ - 1);
#pragma unroll
        for (int j = 0; j < 8; ++j) {
            int i = tid + j * 256;
            int c_l = i >> 4, m8 = (i & 15) * 8;
            int cg = n0 + c_l, h = cg >> 6, d = cg & 63;
            *(bf16x8*)&O[(((size_t)nb * NH + h) * DH + d) * SEQ + kq0 + m8] =
                *(const bf16x8*)&smem[c_l * 136 + m8];
        }
    } else {  // OUT row-major, dual dtype
        unsigned short* Ob = (unsigned short*)C;
        float* Of = (float*)C;
#pragma unroll
        for (int mt = 0; mt < 4; ++mt)
#pragma unroll
            for (int reg = 0; reg < 4; ++reg) {
                int row = m0g + wm * 64 + mt * 16 + quad * 4 + reg;
#pragma unroll
                for (int nt = 0; nt < 4; ++nt) {
                    int c = n0 + wn * 64 + nt * 16 + l16;
                    float v = acc[mt][nt][reg] + bv4[nt];
                    if (isbf) Ob[(size_t)row * DMODEL + c] = f2bf(v);
                    else      Of[(size_t)row * DMODEL + c] = v;
                }
            }
    }
}

// ---------------------------------------------------------------------------
// MFMA flash attention (proven r4, unchanged)
// ---------------------------------------------------------------------------
__global__ __launch_bounds__(256) void attn_mfma(
    const unsigned short* __restrict__ qws, const unsigned short* __restrict__ kws,
    const unsigned short* __restrict__ vtws, const unsigned int* __restrict__ mbits,
    unsigned short* __restrict__ yws)
{
    const int qt   = blockIdx.x;
    const int h    = blockIdx.y;
    const int n    = blockIdx.z;
    const int tid  = threadIdx.x;
    const int wave = tid >> 6;
    const int lane = tid & 63;
    const int l16  = lane & 15;
    const int quad = lane >> 4;

    __shared__ __align__(16) unsigned short Qs[BQ * PAD];
    __shared__ __align__(16) unsigned short Ks[BK * PAD];
    __shared__ __align__(16) unsigned short VTs[DH * PAD];
    __shared__ __align__(16) unsigned short Ps[4][32 * PAD];
    __shared__ unsigned int Ms[BQ][2];

    const size_t base_nh = ((size_t)n * NH + h) * SEQ * DH;
    const size_t base_vt = ((size_t)n * NH + h) * DH * SEQ;
    const int q0 = qt * BQ;
    const unsigned int* mrow_base = mbits + ((size_t)n * SEQ + q0) * (SEQ / 32);

    for (int i = tid; i < BQ * 8; i += 256) {
        int row = i >> 3, seg = (i & 7) * 8;
        *(bf16x8*)&Qs[row * PAD + seg] =
            *(const bf16x8*)&qws[base_nh + (size_t)(q0 + row) * DH + seg];
    }
    __syncthreads();

    bf16x8 af[2][2];
#pragma unroll
    for (int mt = 0; mt < 2; ++mt)
#pragma unroll
        for (int ks = 0; ks < 2; ++ks)
            af[mt][ks] = *(const bf16x8*)&Qs[(wave * 32 + mt * 16 + l16) * PAD + ks * 32 + quad * 8];

    floatx4 O[2][4];
#pragma unroll
    for (int mt = 0; mt < 2; ++mt)
#pragma unroll
        for (int dt = 0; dt < 4; ++dt) O[mt][dt] = floatx4{0.f, 0.f, 0.f, 0.f};
    float mrow[2][4], lrow[2][4];
#pragma unroll
    for (int mt = 0; mt < 2; ++mt)
#pragma unroll
        for (int r = 0; r < 4; ++r) { mrow[mt][r] = -INFINITY; lrow[mt][r] = 0.f; }

    for (int j0 = 0; j0 < SEQ; j0 += BK) {
        for (int i = tid; i < BK * 8; i += 256) {
            int row = i >> 3, seg = (i & 7) * 8;
            *(bf16x8*)&Ks[row * PAD + seg] =
                *(const bf16x8*)&kws[base_nh + (size_t)(j0 + row) * DH + seg];
        }
        for (int i = tid; i < DH * 8; i += 256) {
            int dr = i >> 3, seg = (i & 7) * 8;
            *(bf16x8*)&VTs[dr * PAD + seg] =
                *(const bf16x8*)&vtws[base_vt + (size_t)dr * SEQ + j0 + seg];
        }
        {
            int row = tid >> 1, w = tid & 1;
            Ms[row][w] = mrow_base[(size_t)row * (SEQ / 32) + (j0 >> 5) + w];
        }
        __syncthreads();

        bf16x8 bfK[4][2];
#pragma unroll
        for (int nt = 0; nt < 4; ++nt)
#pragma unroll
            for (int ks = 0; ks < 2; ++ks)
                bfK[nt][ks] = *(const bf16x8*)&Ks[(nt * 16 + l16) * PAD + ks * 32 + quad * 8];

        float S[2][4][4];
#pragma unroll
        for (int mt = 0; mt < 2; ++mt)
#pragma unroll
            for (int nt = 0; nt < 4; ++nt) {
                floatx4 c = {0.f, 0.f, 0.f, 0.f};
                c = __builtin_amdgcn_mfma_f32_16x16x32_bf16(af[mt][0], bfK[nt][0], c, 0, 0, 0);
                c = __builtin_amdgcn_mfma_f32_16x16x32_bf16(af[mt][1], bfK[nt][1], c, 0, 0, 0);
                S[mt][nt][0] = c[0]; S[mt][nt][1] = c[1];
                S[mt][nt][2] = c[2]; S[mt][nt][3] = c[3];
            }

#pragma unroll
        for (int mt = 0; mt < 2; ++mt)
#pragma unroll
            for (int r = 0; r < 4; ++r) {
                int lrowi = wave * 32 + mt * 16 + quad * 4 + r;
#pragma unroll
                for (int nt = 0; nt < 4; ++nt) {
                    unsigned w = Ms[lrowi][nt >> 1];
                    int bit = (w >> ((nt & 1) * 16 + l16)) & 1;
                    S[mt][nt][r] = bit ? -1e9f : S[mt][nt][r] * 0.125f;
                }
            }

#pragma unroll
        for (int mt = 0; mt < 2; ++mt)
#pragma unroll
            for (int r = 0; r < 4; ++r) {
                float mx = S[mt][0][r];
#pragma unroll
                for (int nt = 1; nt < 4; ++nt) mx = fmaxf(mx, S[mt][nt][r]);
                for (int o = 1; o < 16; o <<= 1) mx = fmaxf(mx, __shfl_xor(mx, o));
                float mnew = fmaxf(mrow[mt][r], mx);
                float alpha = __expf(mrow[mt][r] - mnew);
                mrow[mt][r] = mnew;
                float ls = 0.f;
#pragma unroll
                for (int nt = 0; nt < 4; ++nt) {
                    float p = __expf(S[mt][nt][r] - mnew);
                    S[mt][nt][r] = p;
                    ls += p;
                }
                lrow[mt][r] = lrow[mt][r] * alpha + ls;
#pragma unroll
                for (int dt = 0; dt < 4; ++dt) O[mt][dt][r] *= alpha;
            }

#pragma unroll
        for (int mt = 0; mt < 2; ++mt)
#pragma unroll
            for (int nt = 0; nt < 4; ++nt)
#pragma unroll
                for (int r = 0; r < 4; ++r)
                    Ps[wave][(mt * 16 + quad * 4 + r) * PAD + nt * 16 + l16] = f2bf(S[mt][nt][r]);

        bf16x8 pa[2][2], vb[4][2];
#pragma unroll
        for (int mt = 0; mt < 2; ++mt)
#pragma unroll
            for (int ks = 0; ks < 2; ++ks)
                pa[mt][ks] = *(const bf16x8*)&Ps[wave][(mt * 16 + l16) * PAD + ks * 32 + quad * 8];
#pragma unroll
        for (int dt = 0; dt < 4; ++dt)
#pragma unroll
            for (int ks = 0; ks < 2; ++ks)
                vb[dt][ks] = *(const bf16x8*)&VTs[(dt * 16 + l16) * PAD + ks * 32 + quad * 8];
#pragma unroll
        for (int mt = 0; mt < 2; ++mt)
#pragma unroll
            for (int dt = 0; dt < 4; ++dt) {
                O[mt][dt] = __builtin_amdgcn_mfma_f32_16x16x32_bf16(pa[mt][0], vb[dt][0], O[mt][dt], 0, 0, 0);
                O[mt][dt] = __builtin_amdgcn_mfma_f32_16x16x32_bf16(pa[mt][1], vb[dt][1], O[mt][dt], 0, 0, 0);
            }
        __syncthreads();
    }

#pragma unroll
    for (int mt = 0; mt < 2; ++mt)
#pragma unroll
        for (int r = 0; r < 4; ++r)
            for (int o = 1; o < 16; o <<= 1) lrow[mt][r] += __shfl_xor(lrow[mt][r], o);

#pragma unroll
    for (int mt = 0; mt < 2; ++mt)
#pragma unroll
        for (int r = 0; r < 4; ++r) {
            int row = q0 + wave * 32 + mt * 16 + quad * 4 + r;
            float inv = 1.f / lrow[mt][r];
#pragma unroll
            for (int dt = 0; dt < 4; ++dt) {
                int col = h * DH + dt * 16 + l16;
                yws[((size_t)n * SEQ + row) * DMODEL + col] = f2bf(O[mt][dt][r] * inv);
            }
        }
}

extern "C" void kernel_launch(void* const* d_in, const int* in_sizes, int n_in,
                              void* d_out, int out_size, void* d_ws, size_t ws_size,
                              hipStream_t stream) {
    const void* query = d_in[0];
    const void* key_  = d_in[1];
    const void* value = d_in[2];
    const void* mask  = d_in[3];
    const void* Wq = d_in[4];
    const void* bq = d_in[5];
    const void* Wk = d_in[6];
    const void* bk = d_in[7];
    const void* Wv = d_in[8];
    const void* bv = d_in[9];
    const void* Wp = d_in[10];
    const void* bp = d_in[11];

    const size_t per = (size_t)NB * NH * SEQ * DH;  // 4,194,304
    unsigned short* us = (unsigned short*)d_ws;
    unsigned short* qws  = us;
    unsigned short* kws  = us + per;
    unsigned short* vtws = us + 2 * per;
    unsigned short* abf0 = us + 3 * per;   // bf16 query acts; reused as yws after proj
    unsigned short* abf1 = us + 4 * per;
    unsigned short* abf2 = us + 5 * per;
    unsigned short* wt0  = us + 6 * per;                 // 1024x1024 each
    unsigned short* wt1  = wt0 + 1048576;
    unsigned short* wt2  = wt1 + 1048576;
    unsigned short* wt3  = wt2 + 1048576;
    unsigned int* mbits  = (unsigned int*)(wt3 + 1048576);  // 262144 words
    int* flags = (int*)(mbits + (size_t)NB * SEQ * (SEQ / 32));
    unsigned short* yws = abf0;

    detect<<<1, 256, 0, stream>>>((const unsigned short*)query, (const int*)mask, flags);
    conv_a<<<dim3(4096, 1, 3), 256, 0, stream>>>(query, key_, value, abf0, abf1, abf2, flags);
    conv_w<<<dim3(4096, 1, 4), 256, 0, stream>>>(Wq, Wk, Wv, Wp, wt0, wt1, wt2, wt3, flags);
    mask_pack<<<(NB * SEQ * (SEQ / 32)) / 256, 256, 0, stream>>>(mask, mbits, flags);
    gemm_mfma<<<dim3(8, 32, 3), 256, 0, stream>>>(abf0, abf1, abf2, wt0, wt1, wt2,
                                                  bq, bk, bv, qws, kws, vtws, 0, flags);
    attn_mfma<<<dim3(SEQ / BQ, NH, NB), 256, 0, stream>>>(qws, kws, vtws, mbits, yws);
    gemm_mfma<<<dim3(8, 32, 1), 256, 0, stream>>>(yws, yws, yws, wt3, wt3, wt3,
                                                  bp, bp, bp, d_out, d_out, d_out, 3, flags);
}

// Round 6
// 346.067 us; speedup vs baseline: 11.2922x; 1.1071x over previous
//
#include <hip/hip_runtime.h>
#include <hip/hip_bf16.h>

typedef __attribute__((ext_vector_type(8))) __bf16 bf16x8;
typedef __attribute__((ext_vector_type(4))) float floatx4;

#define NB 2
#define SEQ 2048
#define DIN 1024
#define NH 16
#define DH 64
#define DMODEL 1024  // NH*DH
#define BQ 128
#define BK 64
#define PAD 72       // attn LDS row stride (144 B)

__device__ __forceinline__ float bf2f(unsigned short u) {
    return __uint_as_float(((unsigned)u) << 16);
}
__device__ __forceinline__ unsigned short f2bf(float f) {
    unsigned u = __float_as_uint(f);
    unsigned r = (u + 0x7FFFu + ((u >> 16) & 1u)) >> 16;  // RNE
    return (unsigned short)r;
}
__device__ __forceinline__ float ldin(const void* p, size_t idx, int isbf) {
    return isbf ? bf2f(((const unsigned short*)p)[idx]) : ((const float*)p)[idx];
}

// ---------------------------------------------------------------------------
// Per-wave dtype probes (deterministic on pristine inputs; r3-proven logic).
// bf16 data: ~all ushorts have sane exponents. fp32 read as ushort pairs:
// even ushorts are mantissa fragments -> ~15% sane. Threshold at 32/64.
// ---------------------------------------------------------------------------
__device__ __forceinline__ int wave_is_bf16(const void* p) {
    unsigned short u = ((const unsigned short*)p)[2 * (threadIdx.x & 63)];
    int e = (u >> 7) & 0xFF;
    int sane = (u == 0 || (e > 100 && e < 140)) ? 1 : 0;
    return __popcll(__ballot(sane)) >= 32;
}
// int32 mask: all words in {0,1}. byte-bool read as int32: ~1/8 in {0,1}.
__device__ __forceinline__ int wave_mask_is_int(const void* p) {
    int v = ((const int*)p)[threadIdx.x & 63];
    int zo = (v == 0 || v == 1) ? 1 : 0;
    return __popcll(__ballot(zo)) >= 48;
}

// ---------------------------------------------------------------------------
// prep: fused conv_a (acts->bf16) + conv_w (weights->bf16 transposed) +
// mask_pack (1 bit/entry). Single launch.
// blocks [0,12288): conv_a; [12288,28672): conv_w; [28672,29696): mask_pack
// ---------------------------------------------------------------------------
__global__ __launch_bounds__(256) void prep(
    const void* __restrict__ q, const void* __restrict__ k, const void* __restrict__ v,
    const void* __restrict__ mask,
    const void* __restrict__ wq, const void* __restrict__ wk,
    const void* __restrict__ wv, const void* __restrict__ wp,
    unsigned short* __restrict__ a0, unsigned short* __restrict__ a1,
    unsigned short* __restrict__ a2,
    unsigned short* __restrict__ t0, unsigned short* __restrict__ t1,
    unsigned short* __restrict__ t2, unsigned short* __restrict__ t3,
    unsigned int* __restrict__ mbits)
{
    const int b = blockIdx.x;
    const int tid = threadIdx.x;
    if (b < 12288) {                       // ---- activations -> bf16 ----
        int z = b >> 12, blk = b & 4095;
        const void* src = (z == 0) ? q : (z == 1) ? k : v;
        unsigned short* dst = (z == 0) ? a0 : (z == 1) ? a1 : a2;
        int isbf = wave_is_bf16(src);
        size_t i = ((size_t)blk * 256 + tid) * 4;
        if (isbf) {
            *(ushort4*)&dst[i] = *(const ushort4*)((const unsigned short*)src + i);
        } else {
            float4 f = *(const float4*)((const float*)src + i);
            ushort4 o;
            o.x = f2bf(f.x); o.y = f2bf(f.y); o.z = f2bf(f.z); o.w = f2bf(f.w);
            *(ushort4*)&dst[i] = o;
        }
    } else if (b < 28672) {                // ---- weights -> bf16 WT[c][m] ----
        int zb = b - 12288;
        int z = zb >> 12, blk = zb & 4095;
        const void* src = (z == 0) ? wq : (z == 1) ? wk : (z == 2) ? wv : wp;
        unsigned short* dst = (z == 0) ? t0 : (z == 1) ? t1 : (z == 2) ? t2 : t3;
        int isbf = wave_is_bf16(src);
        int idx = blk * 256 + tid;
        int m = idx & 1023, c = idx >> 10;
        size_t sidx;
        if (z < 3) { int h = c >> 6, d = c & 63; sidx = (size_t)h * 65536 + (size_t)m * 64 + d; }
        else       { sidx = (size_t)m * 1024 + c; }
        dst[idx] = f2bf(ldin(src, sidx, isbf));
    } else {                               // ---- mask -> bits ----
        int blk = b - 28672;
        int w = blk * 256 + tid;
        int is_int = wave_mask_is_int(mask);
        unsigned bits = 0;
        if (is_int) {
            const int4* p = (const int4*)mask + (size_t)w * 8;
#pragma unroll
            for (int g = 0; g < 8; ++g) {
                int4 vv = p[g];
                bits |= (unsigned)(vv.x != 0) << (g * 4 + 0);
                bits |= (unsigned)(vv.y != 0) << (g * 4 + 1);
                bits |= (unsigned)(vv.z != 0) << (g * 4 + 2);
                bits |= (unsigned)(vv.w != 0) << (g * 4 + 3);
            }
        } else {
            const uint4* p = (const uint4*)mask + (size_t)w * 2;
#pragma unroll
            for (int g = 0; g < 2; ++g) {
                uint4 vv = p[g];
                unsigned ws4[4] = {vv.x, vv.y, vv.z, vv.w};
#pragma unroll
                for (int c = 0; c < 4; ++c)
#pragma unroll
                    for (int bb = 0; bb < 4; ++bb)
                        bits |= (unsigned)(((ws4[c] >> (8 * bb)) & 0xFFu) != 0)
                                << (g * 16 + c * 4 + bb);
            }
        }
        mbits[w] = bits;
    }
}

// ---------------------------------------------------------------------------
// Unified MFMA GEMM (r5-proven): C(4096x1024)=A(bf16) x BT(bf16)^T + bias.
// 128x128 tile, BK=64, 4 waves x (64x64). mode: 0/1 Q/K->(n,h,k,d);
// 2 V->(n,h,d,k) via LDS transpose; 3 OUT row-major fp32/bf16.
// ---------------------------------------------------------------------------
__global__ __launch_bounds__(256) void gemm_mfma(
    const unsigned short* __restrict__ A0, const unsigned short* __restrict__ A1,
    const unsigned short* __restrict__ A2,
    const unsigned short* __restrict__ B0, const unsigned short* __restrict__ B1,
    const unsigned short* __restrict__ B2,
    const void* __restrict__ bias0, const void* __restrict__ bias1,
    const void* __restrict__ bias2,
    void* __restrict__ C0, void* __restrict__ C1, void* __restrict__ C2,
    int mode0)
{
    const int z = blockIdx.z;
    const unsigned short* A  = (z == 0) ? A0 : (z == 1) ? A1 : A2;
    const unsigned short* BT = (z == 0) ? B0 : (z == 1) ? B1 : B2;
    const void* bias = (z == 0) ? bias0 : (z == 1) ? bias1 : bias2;
    void* C = (z == 0) ? C0 : (z == 1) ? C1 : C2;
    const int mode = mode0 + z;
    const int isbf = wave_is_bf16(bias);

    const int n0  = blockIdx.x * 128;
    const int m0g = blockIdx.y * 128;
    const int tid = threadIdx.x;
    const int wave = tid >> 6, lane = tid & 63;
    const int l16 = lane & 15, quad = lane >> 4;
    const int wm = wave & 1, wn = wave >> 1;

    __shared__ __align__(16) unsigned short smem[17408];
    unsigned short* As = smem;
    unsigned short* Bs = smem + 8192;

    floatx4 acc[4][4];
#pragma unroll
    for (int mt = 0; mt < 4; ++mt)
#pragma unroll
        for (int nt = 0; nt < 4; ++nt) acc[mt][nt] = floatx4{0.f, 0.f, 0.f, 0.f};

    for (int kk = 0; kk < 1024; kk += 64) {
#pragma unroll
        for (int j = 0; j < 4; ++j) {
            int i = tid + j * 256;
            int row = i >> 3, seg = (i & 7) * 8;
            *(bf16x8*)&As[row * 64 + seg] = *(const bf16x8*)&A[(size_t)(m0g + row) * 1024 + kk + seg];
            *(bf16x8*)&Bs[row * 64 + seg] = *(const bf16x8*)&BT[(size_t)(n0 + row) * 1024 + kk + seg];
        }
        __syncthreads();
#pragma unroll
        for (int ks = 0; ks < 2; ++ks) {
            bf16x8 af[4], bf[4];
#pragma unroll
            for (int mt = 0; mt < 4; ++mt)
                af[mt] = *(const bf16x8*)&As[(wm * 64 + mt * 16 + l16) * 64 + ks * 32 + quad * 8];
#pragma unroll
            for (int nt = 0; nt < 4; ++nt)
                bf[nt] = *(const bf16x8*)&Bs[(wn * 64 + nt * 16 + l16) * 64 + ks * 32 + quad * 8];
#pragma unroll
            for (int mt = 0; mt < 4; ++mt)
#pragma unroll
                for (int nt = 0; nt < 4; ++nt)
                    acc[mt][nt] = __builtin_amdgcn_mfma_f32_16x16x32_bf16(af[mt], bf[nt], acc[mt][nt], 0, 0, 0);
        }
        __syncthreads();
    }

    float bv4[4];
#pragma unroll
    for (int nt = 0; nt < 4; ++nt)
        bv4[nt] = ldin(bias, n0 + wn * 64 + nt * 16 + l16, isbf);

    if (mode <= 1) {  // Q/K -> (n,h,k,d)
        unsigned short* O = (unsigned short*)C;
#pragma unroll
        for (int mt = 0; mt < 4; ++mt)
#pragma unroll
            for (int reg = 0; reg < 4; ++reg) {
                int row = m0g + wm * 64 + mt * 16 + quad * 4 + reg;
                int nb = row >> 11, kq = row & (SEQ - 1);
#pragma unroll
                for (int nt = 0; nt < 4; ++nt) {
                    int c = n0 + wn * 64 + nt * 16 + l16;
                    int h = c >> 6, d = c & 63;
                    O[(((size_t)nb * NH + h) * SEQ + kq) * DH + d] = f2bf(acc[mt][nt][reg] + bv4[nt]);
                }
            }
    } else if (mode == 2) {  // V -> (n,h,d,k) via LDS transpose
#pragma unroll
        for (int mt = 0; mt < 4; ++mt)
#pragma unroll
            for (int nt = 0; nt < 4; ++nt)
#pragma unroll
                for (int reg = 0; reg < 4; ++reg) {
                    int m_l = wm * 64 + mt * 16 + quad * 4 + reg;
                    int c_l = wn * 64 + nt * 16 + l16;
                    smem[c_l * 136 + m_l] = f2bf(acc[mt][nt][reg] + bv4[nt]);
                }
        __syncthreads();
        unsigned short* O = (unsigned short*)C;
        int nb = m0g >> 11;
        int kq0 = m0g & (SEQ - 1);
#pragma unroll
        for (int j = 0; j < 8; ++j) {
            int i = tid + j * 256;
            int c_l = i >> 4, m8 = (i & 15) * 8;
            int cg = n0 + c_l, h = cg >> 6, d = cg & 63;
            *(bf16x8*)&O[(((size_t)nb * NH + h) * DH + d) * SEQ + kq0 + m8] =
                *(const bf16x8*)&smem[c_l * 136 + m8];
        }
    } else {  // OUT row-major, dual dtype
        unsigned short* Ob = (unsigned short*)C;
        float* Of = (float*)C;
#pragma unroll
        for (int mt = 0; mt < 4; ++mt)
#pragma unroll
            for (int reg = 0; reg < 4; ++reg) {
                int row = m0g + wm * 64 + mt * 16 + quad * 4 + reg;
#pragma unroll
                for (int nt = 0; nt < 4; ++nt) {
                    int c = n0 + wn * 64 + nt * 16 + l16;
                    float v = acc[mt][nt][reg] + bv4[nt];
                    if (isbf) Ob[(size_t)row * DMODEL + c] = f2bf(v);
                    else      Of[(size_t)row * DMODEL + c] = v;
                }
            }
    }
}

// ---------------------------------------------------------------------------
// MFMA flash attention, pipelined: double-buffered K/V^T/mask LDS, next-tile
// global loads issued before current-tile compute, ONE barrier per K-tile.
// Q fragments load directly from global (no Q LDS). P via per-wave LDS
// (truncating bf16 — no barrier, program-order + lgkmcnt only).
// ---------------------------------------------------------------------------
__global__ __launch_bounds__(256) void attn_mfma(
    const unsigned short* __restrict__ qws, const unsigned short* __restrict__ kws,
    const unsigned short* __restrict__ vtws, const unsigned int* __restrict__ mbits,
    unsigned short* __restrict__ yws)
{
    const int qt   = blockIdx.x;
    const int h    = blockIdx.y;
    const int n    = blockIdx.z;
    const int tid  = threadIdx.x;
    const int wave = tid >> 6;
    const int lane = tid & 63;
    const int l16  = lane & 15;
    const int quad = lane >> 4;

    __shared__ __align__(16) unsigned short Ks[2][BK * PAD];   // [key][d]
    __shared__ __align__(16) unsigned short VTs[2][DH * PAD];  // [d][key]
    __shared__ __align__(16) unsigned short Ps[4][32 * PAD];   // per-wave [row][key]
    __shared__ unsigned int Ms[2][BQ][2];

    const size_t base_nh = ((size_t)n * NH + h) * SEQ * DH;
    const size_t base_vt = ((size_t)n * NH + h) * DH * SEQ;
    const int q0 = qt * BQ;
    const unsigned int* mrow_base = mbits + ((size_t)n * SEQ + q0) * (SEQ / 32);

    // staging thread geometry: i = tid + j*256, row=i>>3, seg=(i&7)*8
    const int srow = tid >> 3, sseg = (tid & 7) * 8;
    const int mr = tid >> 1, mw = tid & 1;

    // Q fragments direct from global: A[m=l16][k=quad*8+j], rows wave*32+mt*16+l16
    bf16x8 af[2][2];
#pragma unroll
    for (int mt = 0; mt < 2; ++mt) {
        const unsigned short* qp =
            qws + base_nh + (size_t)(q0 + wave * 32 + mt * 16 + l16) * DH + quad * 8;
        af[mt][0] = *(const bf16x8*)qp;
        af[mt][1] = *(const bf16x8*)(qp + 32);
    }

    // prologue: stage tile 0
    {
#pragma unroll
        for (int j = 0; j < 2; ++j) {
            int row = srow + j * 32;
            *(bf16x8*)&Ks[0][row * PAD + sseg] =
                *(const bf16x8*)&kws[base_nh + (size_t)row * DH + sseg];
            *(bf16x8*)&VTs[0][row * PAD + sseg] =
                *(const bf16x8*)&vtws[base_vt + (size_t)row * SEQ + sseg];
        }
        Ms[0][mr][mw] = mrow_base[(size_t)mr * (SEQ / 32) + mw];
    }

    floatx4 O[2][4];
#pragma unroll
    for (int mt = 0; mt < 2; ++mt)
#pragma unroll
        for (int dt = 0; dt < 4; ++dt) O[mt][dt] = floatx4{0.f, 0.f, 0.f, 0.f};
    float mrow[2][4], lrow[2][4];
#pragma unroll
    for (int mt = 0; mt < 2; ++mt)
#pragma unroll
        for (int r = 0; r < 4; ++r) { mrow[mt][r] = -INFINITY; lrow[mt][r] = 0.f; }

    __syncthreads();

    for (int it = 0; it < SEQ / BK; ++it) {
        const int cur = it & 1;
        const bool has_next = (it + 1) < (SEQ / BK);
        const int j0n = (it + 1) * BK;

        // issue next tile's global loads (in flight across compute)
        bf16x8 nk[2], nv[2];
        unsigned int nm = 0;
        if (has_next) {
#pragma unroll
            for (int j = 0; j < 2; ++j) {
                int row = srow + j * 32;
                nk[j] = *(const bf16x8*)&kws[base_nh + (size_t)(j0n + row) * DH + sseg];
                nv[j] = *(const bf16x8*)&vtws[base_vt + (size_t)row * SEQ + j0n + sseg];
            }
            nm = mrow_base[(size_t)mr * (SEQ / 32) + (j0n >> 5) + mw];
        }

        // ---- QK^T ----
        bf16x8 bfK[4][2];
#pragma unroll
        for (int nt = 0; nt < 4; ++nt)
#pragma unroll
            for (int ks = 0; ks < 2; ++ks)
                bfK[nt][ks] = *(const bf16x8*)&Ks[cur][(nt * 16 + l16) * PAD + ks * 32 + quad * 8];

        float S[2][4][4];
#pragma unroll
        for (int mt = 0; mt < 2; ++mt)
#pragma unroll
            for (int nt = 0; nt < 4; ++nt) {
                floatx4 c = {0.f, 0.f, 0.f, 0.f};
                c = __builtin_amdgcn_mfma_f32_16x16x32_bf16(af[mt][0], bfK[nt][0], c, 0, 0, 0);
                c = __builtin_amdgcn_mfma_f32_16x16x32_bf16(af[mt][1], bfK[nt][1], c, 0, 0, 0);
                S[mt][nt][0] = c[0]; S[mt][nt][1] = c[1];
                S[mt][nt][2] = c[2]; S[mt][nt][3] = c[3];
            }

        // ---- mask + scale (reference order: masked := exactly -1e9) ----
#pragma unroll
        for (int mt = 0; mt < 2; ++mt)
#pragma unroll
            for (int r = 0; r < 4; ++r) {
                int lrowi = wave * 32 + mt * 16 + quad * 4 + r;
#pragma unroll
                for (int nt = 0; nt < 4; ++nt) {
                    unsigned w = Ms[cur][lrowi][nt >> 1];
                    int bit = (w >> ((nt & 1) * 16 + l16)) & 1;
                    S[mt][nt][r] = bit ? -1e9f : S[mt][nt][r] * 0.125f;
                }
            }

        // ---- online softmax ----
#pragma unroll
        for (int mt = 0; mt < 2; ++mt)
#pragma unroll
            for (int r = 0; r < 4; ++r) {
                float mx = S[mt][0][r];
#pragma unroll
                for (int nt = 1; nt < 4; ++nt) mx = fmaxf(mx, S[mt][nt][r]);
                for (int o = 1; o < 16; o <<= 1) mx = fmaxf(mx, __shfl_xor(mx, o));
                float mnew = fmaxf(mrow[mt][r], mx);
                float alpha = __expf(mrow[mt][r] - mnew);
                mrow[mt][r] = mnew;
                float ls = 0.f;
#pragma unroll
                for (int nt = 0; nt < 4; ++nt) {
                    float p = __expf(S[mt][nt][r] - mnew);
                    S[mt][nt][r] = p;
                    ls += p;
                }
                lrow[mt][r] = lrow[mt][r] * alpha + ls;
#pragma unroll
                for (int dt = 0; dt < 4; ++dt) O[mt][dt][r] *= alpha;
            }

        // ---- P -> per-wave LDS (truncating bf16; p>=0 so trunc==toward-zero) ----
#pragma unroll
        for (int mt = 0; mt < 2; ++mt)
#pragma unroll
            for (int nt = 0; nt < 4; ++nt)
#pragma unroll
                for (int r = 0; r < 4; ++r)
                    Ps[wave][(mt * 16 + quad * 4 + r) * PAD + nt * 16 + l16] =
                        (unsigned short)(__float_as_uint(S[mt][nt][r]) >> 16);

        // ---- PV ----
        bf16x8 pa[2][2], vb[4][2];
#pragma unroll
        for (int mt = 0; mt < 2; ++mt)
#pragma unroll
            for (int ks = 0; ks < 2; ++ks)
                pa[mt][ks] = *(const bf16x8*)&Ps[wave][(mt * 16 + l16) * PAD + ks * 32 + quad * 8];
#pragma unroll
        for (int dt = 0; dt < 4; ++dt)
#pragma unroll
            for (int ks = 0; ks < 2; ++ks)
                vb[dt][ks] = *(const bf16x8*)&VTs[cur][(dt * 16 + l16) * PAD + ks * 32 + quad * 8];
#pragma unroll
        for (int mt = 0; mt < 2; ++mt)
#pragma unroll
            for (int dt = 0; dt < 4; ++dt) {
                O[mt][dt] = __builtin_amdgcn_mfma_f32_16x16x32_bf16(pa[mt][0], vb[dt][0], O[mt][dt], 0, 0, 0);
                O[mt][dt] = __builtin_amdgcn_mfma_f32_16x16x32_bf16(pa[mt][1], vb[dt][1], O[mt][dt], 0, 0, 0);
            }

        // ---- write next tile to the other buffer, single barrier ----
        if (has_next) {
            const int nxt = cur ^ 1;
#pragma unroll
            for (int j = 0; j < 2; ++j) {
                int row = srow + j * 32;
                *(bf16x8*)&Ks[nxt][row * PAD + sseg] = nk[j];
                *(bf16x8*)&VTs[nxt][row * PAD + sseg] = nv[j];
            }
            Ms[nxt][mr][mw] = nm;
        }
        __syncthreads();
    }

    // epilogue: reduce l across 16 lanes per row, normalize, store
#pragma unroll
    for (int mt = 0; mt < 2; ++mt)
#pragma unroll
        for (int r = 0; r < 4; ++r)
            for (int o = 1; o < 16; o <<= 1) lrow[mt][r] += __shfl_xor(lrow[mt][r], o);

#pragma unroll
    for (int mt = 0; mt < 2; ++mt)
#pragma unroll
        for (int r = 0; r < 4; ++r) {
            int row = q0 + wave * 32 + mt * 16 + quad * 4 + r;
            float inv = 1.f / lrow[mt][r];
#pragma unroll
            for (int dt = 0; dt < 4; ++dt) {
                int col = h * DH + dt * 16 + l16;
                yws[((size_t)n * SEQ + row) * DMODEL + col] = f2bf(O[mt][dt][r] * inv);
            }
        }
}

extern "C" void kernel_launch(void* const* d_in, const int* in_sizes, int n_in,
                              void* d_out, int out_size, void* d_ws, size_t ws_size,
                              hipStream_t stream) {
    const void* query = d_in[0];
    const void* key_  = d_in[1];
    const void* value = d_in[2];
    const void* mask  = d_in[3];
    const void* Wq = d_in[4];
    const void* bq = d_in[5];
    const void* Wk = d_in[6];
    const void* bk = d_in[7];
    const void* Wv = d_in[8];
    const void* bv = d_in[9];
    const void* Wp = d_in[10];
    const void* bp = d_in[11];

    const size_t per = (size_t)NB * NH * SEQ * DH;  // 4,194,304
    unsigned short* us = (unsigned short*)d_ws;
    unsigned short* qws  = us;
    unsigned short* kws  = us + per;
    unsigned short* vtws = us + 2 * per;
    unsigned short* abf0 = us + 3 * per;   // bf16 query acts; reused as yws after proj
    unsigned short* abf1 = us + 4 * per;
    unsigned short* abf2 = us + 5 * per;
    unsigned short* wt0  = us + 6 * per;
    unsigned short* wt1  = wt0 + 1048576;
    unsigned short* wt2  = wt1 + 1048576;
    unsigned short* wt3  = wt2 + 1048576;
    unsigned int* mbits  = (unsigned int*)(wt3 + 1048576);  // 262144 words
    unsigned short* yws = abf0;

    prep<<<dim3(29696), 256, 0, stream>>>(query, key_, value, mask,
                                          Wq, Wk, Wv, Wp,
                                          abf0, abf1, abf2,
                                          wt0, wt1, wt2, wt3, mbits);
    gemm_mfma<<<dim3(8, 32, 3), 256, 0, stream>>>(abf0, abf1, abf2, wt0, wt1, wt2,
                                                  bq, bk, bv, qws, kws, vtws, 0);
    attn_mfma<<<dim3(SEQ / BQ, NH, NB), 256, 0, stream>>>(qws, kws, vtws, mbits, yws);
    gemm_mfma<<<dim3(8, 32, 1), 256, 0, stream>>>(yws, yws, yws, wt3, wt3, wt3,
                                                  bp, bp, bp, d_out, d_out, d_out, 3);
}